// Round 3
// baseline (365.426 us; speedup 1.0000x reference)
//
#include <hip/hip_runtime.h>
#include <stdint.h>

// ---------------------------------------------------------------------------
// kWTA: threshold = K-th largest of N fp32; out[i] = in[i] < thr ? 0 : in[i]
//
// Normal-data insight: a full 12-bit-key histogram serializes on ~24 hot LDS
// bins (exponent concentration). Instead: sample 256K elements to pick an
// 8-bit-bucket cutoff B8 so only the ~1.6% tail is histogrammed exactly.
//
//   K1 k_sample:    1MB sample -> 256-bin hist -> last block picks B8
//   K2 k_hist_tail: full read; 4096-bin hist of tail only; last block selects
//                   threshold bucket + rank (sets fallback flag if miss)
//   K3 k_fb:        early-exit unless flag; full hist + select (pathological)
//   K4 k_apply_gather: above-bucket copy / below zero / in-bucket -> 0 + push
//   K5 k_final:     exact 20-bit radix select over candidates + scatter-restore
// ---------------------------------------------------------------------------

#define HIST_BINS 4096
#define SAMPLE_BLOCKS 64
#define SAMPLE_F4_PER_BLOCK 1024            // 256 thr * 4 float4
#define SAMPLE_M (SAMPLE_BLOCKS * SAMPLE_F4_PER_BLOCK * 4)  // 262144 elements

// ws layout (32-bit word offsets)
#define TAIL_HIST_OFF 0
#define FB_HIST_OFF   4096
#define SAMP_HIST_OFF 8192   // 256 words
#define DONE_SAMP     8448
#define DONE_TAIL     8449
#define DONE_FB       8450
#define FB_FLAG       8451
#define B8_OFF        8452
#define CTRL_OFF      8456   // [0]=gather ctr [1]=sel bucket [2]=want [3]=thr
#define CAND_OFF      8472
#define ZERO_WORDS    8472

__device__ __forceinline__ uint32_t f2key(float x) {
  uint32_t u = __float_as_uint(x);
  return (u & 0x80000000u) ? ~u : (u | 0x80000000u);  // larger key <=> larger float
}
__device__ __forceinline__ float key2f(uint32_t k) {
  uint32_t u = (k & 0x80000000u) ? (k & 0x7fffffffu) : ~k;
  return __uint_as_float(u);
}

// Ballot-aggregated LDS histogram add (8-bit bin): one atomic per distinct
// bin per wave instead of per lane — kills same-address serialization.
__device__ __forceinline__ void histAdd8(uint32_t* lh, uint32_t bin) {
  unsigned long long peers = __ballot(1);
#pragma unroll
  for (int b = 0; b < 8; b++) {
    unsigned long long vote = __ballot((bin >> b) & 1u);
    peers &= ((bin >> b) & 1u) ? vote : ~vote;
  }
  unsigned lane = threadIdx.x & 63u;
  if (lane == (unsigned)(__ffsll((long long)peers) - 1))
    atomicAdd(&lh[bin], (uint32_t)__popcll(peers));
}

// One 256-thread block: suffix-scan a 4096-bin hist (gh, global) from the top;
// write ctrl[1]=bucket, ctrl[2]=rank-within-bucket. Returns miss via flag.
__device__ void select4096(const uint32_t* __restrict__ gh, uint32_t K,
                           uint32_t* __restrict__ ctrl,
                           uint32_t* __restrict__ fbflag,  // null = clamp mode
                           uint32_t* lh, uint32_t* chunk) {
  int t = threadIdx.x;
  for (int i = t; i < HIST_BINS; i += 256) lh[i] = gh[i];
  __syncthreads();
  uint32_t s = 0;
#pragma unroll
  for (int i = 0; i < 16; i++) s += lh[t * 16 + i];
  chunk[t] = s;
  __syncthreads();
  if (t == 0) {
    uint32_t above = 0;
    int sel = -1;
    for (int c = 255; c >= 0; c--) {
      if (above + chunk[c] >= K) { sel = c; break; }
      above += chunk[c];
    }
    if (sel < 0) {
      if (fbflag) { *fbflag = 1u; }           // K-th not in tail -> fallback
      else { ctrl[1] = 0u; ctrl[2] = 0xFFFFFFFFu; }  // K>=N: keep everything
    } else {
      int bsel = sel * 16;
      for (int b = sel * 16 + 15; b >= sel * 16; b--) {
        uint32_t c = lh[b];
        if (above + c >= K) { bsel = b; break; }
        above += c;
      }
      ctrl[1] = (uint32_t)bsel;
      ctrl[2] = K - above;  // 1-based rank within bucket (from the top)
    }
  }
}

__global__ void k_sample(const float4* __restrict__ in, int n4,
                         const int* __restrict__ kptr, uint32_t n,
                         uint32_t* __restrict__ ws) {
  __shared__ uint32_t lh[256];
  __shared__ uint32_t s_last;
  int t = threadIdx.x;
  if (t < 256) lh[t] = 0;
  __syncthreads();
  if (n4 >= SAMPLE_F4_PER_BLOCK) {
    int chunkf4 = n4 / SAMPLE_BLOCKS;
    int base = blockIdx.x * chunkf4;
    if (base + SAMPLE_F4_PER_BLOCK > n4) base = n4 - SAMPLE_F4_PER_BLOCK;
#pragma unroll
    for (int j = 0; j < 4; j++) {
      float4 v = in[base + t + j * 256];
      histAdd8(lh, f2key(v.x) >> 24);
      histAdd8(lh, f2key(v.y) >> 24);
      histAdd8(lh, f2key(v.z) >> 24);
      histAdd8(lh, f2key(v.w) >> 24);
    }
  }
  __syncthreads();
  if (t < 256) {
    uint32_t c = lh[t];
    if (c) atomicAdd(&ws[SAMP_HIST_OFF + t], c);
  }
  __threadfence();
  if (t == 0) s_last = atomicAdd(&ws[DONE_SAMP], 1u);
  __syncthreads();
  if (s_last == SAMPLE_BLOCKS - 1) {
    __threadfence();
    if (t < 256) lh[t] = ws[SAMP_HIST_OFF + t];
    __syncthreads();
    if (t == 0) {
      int kv = kptr[0];
      uint32_t K = (kv < 1) ? 1u : (uint32_t)kv;
      uint64_t tgt64 = ((uint64_t)K * SAMPLE_M / (n ? n : 1u)) * 2u + 4096u;
      uint32_t target = (tgt64 > SAMPLE_M) ? (uint32_t)SAMPLE_M : (uint32_t)tgt64;
      if (target < 4096u) target = 4096u;
      uint32_t sum = 0; uint32_t b8 = 0;
      for (int b = 255; b >= 0; b--) {
        sum += lh[b];
        if (sum >= target) { b8 = (uint32_t)b; break; }
      }
      ws[B8_OFF] = b8;  // if sample never reached target, b8=0 -> tail = all
    }
  }
}

__global__ void k_hist_tail(const float4* __restrict__ in, int n4, int ntail,
                            const float* __restrict__ in_s,
                            const int* __restrict__ kptr,
                            uint32_t* __restrict__ ws, int nblocks, uint32_t n) {
  __shared__ uint32_t lh[HIST_BINS];
  __shared__ uint32_t chunk[256];
  __shared__ uint32_t s_last;
  int t = threadIdx.x;
  for (int i = t; i < HIST_BINS; i += blockDim.x) lh[i] = 0;
  __syncthreads();
  uint32_t cut = ws[B8_OFF] << 4;  // prior-kernel write: visible at launch boundary
  int stride = gridDim.x * blockDim.x;
  for (int i = blockIdx.x * blockDim.x + t; i < n4; i += stride) {
    float4 v = in[i];
    uint32_t k0 = f2key(v.x) >> 20, k1 = f2key(v.y) >> 20;
    uint32_t k2 = f2key(v.z) >> 20, k3 = f2key(v.w) >> 20;
    if (k0 >= cut) atomicAdd(&lh[k0], 1u);
    if (k1 >= cut) atomicAdd(&lh[k1], 1u);
    if (k2 >= cut) atomicAdd(&lh[k2], 1u);
    if (k3 >= cut) atomicAdd(&lh[k3], 1u);
  }
  if (blockIdx.x == 0 && t < ntail) {
    uint32_t kk = f2key(in_s[n4 * 4 + t]) >> 20;
    if (kk >= cut) atomicAdd(&lh[kk], 1u);
  }
  __syncthreads();
  for (int i = t; i < HIST_BINS; i += blockDim.x) {
    uint32_t c = lh[i];
    if (c) atomicAdd(&ws[TAIL_HIST_OFF + i], c);
  }
  __threadfence();
  if (t == 0) s_last = atomicAdd(&ws[DONE_TAIL], 1u);
  __syncthreads();
  if (s_last == (uint32_t)(nblocks - 1)) {
    __threadfence();
    int kv = kptr[0];
    uint32_t K = (kv < 1) ? 1u : (uint32_t)kv;
    if (K > n) K = n;
    select4096(ws + TAIL_HIST_OFF, K, ws + CTRL_OFF, ws + FB_FLAG, lh, chunk);
  }
}

// Pathological-data fallback: full histogram (plain atomics, slow but exact).
__global__ void k_fb(const float4* __restrict__ in, int n4, int ntail,
                     const float* __restrict__ in_s,
                     const int* __restrict__ kptr,
                     uint32_t* __restrict__ ws, int nblocks, uint32_t n) {
  __shared__ uint32_t lh[HIST_BINS];
  __shared__ uint32_t chunk[256];
  __shared__ uint32_t s_flag, s_last;
  int t = threadIdx.x;
  if (t == 0) s_flag = ws[FB_FLAG];
  __syncthreads();
  if (!s_flag) return;
  for (int i = t; i < HIST_BINS; i += blockDim.x) lh[i] = 0;
  __syncthreads();
  int stride = gridDim.x * blockDim.x;
  for (int i = blockIdx.x * blockDim.x + t; i < n4; i += stride) {
    float4 v = in[i];
    atomicAdd(&lh[f2key(v.x) >> 20], 1u);
    atomicAdd(&lh[f2key(v.y) >> 20], 1u);
    atomicAdd(&lh[f2key(v.z) >> 20], 1u);
    atomicAdd(&lh[f2key(v.w) >> 20], 1u);
  }
  if (blockIdx.x == 0 && t < ntail)
    atomicAdd(&lh[f2key(in_s[n4 * 4 + t]) >> 20], 1u);
  __syncthreads();
  for (int i = t; i < HIST_BINS; i += blockDim.x) {
    uint32_t c = lh[i];
    if (c) atomicAdd(&ws[FB_HIST_OFF + i], c);
  }
  __threadfence();
  if (t == 0) s_last = atomicAdd(&ws[DONE_FB], 1u);
  __syncthreads();
  if (s_last == (uint32_t)(nblocks - 1)) {
    __threadfence();
    int kv = kptr[0];
    uint32_t K = (kv < 1) ? 1u : (uint32_t)kv;
    if (K > n) K = n;
    select4096(ws + FB_HIST_OFF, K, ws + CTRL_OFF, nullptr, lh, chunk);
  }
}

// Fused apply + gather: definite elements written immediately; threshold-bucket
// elements provisionally zeroed and recorded (key, flat index) for K5's fixup.
__global__ void k_apply_gather(const float4* __restrict__ in,
                               float4* __restrict__ out, int n4, int ntail,
                               const float* __restrict__ in_s,
                               float* __restrict__ out_s,
                               uint32_t* __restrict__ ctrl,
                               uint32_t* __restrict__ keys,
                               uint32_t* __restrict__ idxs, uint32_t cap) {
  uint32_t sel = ctrl[1];
  int stride = gridDim.x * blockDim.x;
  for (int i = blockIdx.x * blockDim.x + threadIdx.x; i < n4; i += stride) {
    float4 v = in[i];
    uint32_t k0 = f2key(v.x), k1 = f2key(v.y), k2 = f2key(v.z), k3 = f2key(v.w);
    uint32_t b0 = k0 >> 20, b1 = k1 >> 20, b2 = k2 >> 20, b3 = k3 >> 20;
    float4 r;
    r.x = (b0 > sel) ? v.x : 0.0f;
    r.y = (b1 > sel) ? v.y : 0.0f;
    r.z = (b2 > sel) ? v.z : 0.0f;
    r.w = (b3 > sel) ? v.w : 0.0f;
    if (b0 == sel) { uint32_t p = atomicAdd(&ctrl[0], 1u); if (p < cap) { keys[p] = k0; idxs[p] = 4u * i + 0u; } }
    if (b1 == sel) { uint32_t p = atomicAdd(&ctrl[0], 1u); if (p < cap) { keys[p] = k1; idxs[p] = 4u * i + 1u; } }
    if (b2 == sel) { uint32_t p = atomicAdd(&ctrl[0], 1u); if (p < cap) { keys[p] = k2; idxs[p] = 4u * i + 2u; } }
    if (b3 == sel) { uint32_t p = atomicAdd(&ctrl[0], 1u); if (p < cap) { keys[p] = k3; idxs[p] = 4u * i + 3u; } }
    __builtin_nontemporal_store(r.x, &((float*)&out[i])[0]);
    __builtin_nontemporal_store(r.y, &((float*)&out[i])[1]);
    __builtin_nontemporal_store(r.z, &((float*)&out[i])[2]);
    __builtin_nontemporal_store(r.w, &((float*)&out[i])[3]);
  }
  if (blockIdx.x == 0 && (int)threadIdx.x < ntail) {
    int j = n4 * 4 + threadIdx.x;
    float x = in_s[j];
    uint32_t kk = f2key(x);
    uint32_t bb = kk >> 20;
    out_s[j] = (bb > sel) ? x : 0.0f;
    if (bb == sel) { uint32_t p = atomicAdd(&ctrl[0], 1u); if (p < cap) { keys[p] = kk; idxs[p] = (uint32_t)j; } }
  }
}

// Exact 20-bit radix select over the candidates, then scatter-restore winners.
__global__ void __launch_bounds__(1024) k_final(uint32_t* __restrict__ ctrl,
                                                const uint32_t* __restrict__ keys,
                                                const uint32_t* __restrict__ idxs,
                                                uint32_t cap,
                                                float* __restrict__ out_s) {
  __shared__ uint32_t sh[8192];
  __shared__ uint32_t red[16];
  __shared__ uint32_t s_p, s_want;
  int t = threadIdx.x;
  uint32_t n = ctrl[0]; if (n > cap) n = cap;
  bool useLds = (n <= 8192);
  if (useLds) for (uint32_t i = t; i < n; i += blockDim.x) sh[i] = keys[i];
  if (t == 0) { s_p = ctrl[1] << 20; s_want = ctrl[2]; }
  __syncthreads();
  uint32_t p = s_p, want = s_want;
  for (int bit = 19; bit >= 0; bit--) {
    uint32_t test = p | (1u << bit);
    uint32_t hi = test >> bit;
    uint32_t cnt = 0;
    for (uint32_t i = t; i < n; i += blockDim.x) {
      uint32_t kk = useLds ? sh[i] : keys[i];
      cnt += ((kk >> bit) == hi) ? 1u : 0u;
    }
    for (int off = 32; off; off >>= 1) cnt += __shfl_down((int)cnt, off);
    int wave = t >> 6, lane = t & 63;
    if (lane == 0) red[wave] = cnt;
    __syncthreads();
    if (t == 0) {
      uint32_t tot = 0;
      for (int w = 0; w < 16; w++) tot += red[w];
      if (tot >= want) p = test; else want -= tot;
      s_p = p; s_want = want;
    }
    __syncthreads();
    p = s_p; want = s_want;
  }
  if (t == 0) ctrl[3] = __float_as_uint(key2f(p));
  // fixup: restore in-bucket elements at or above the exact threshold
  for (uint32_t i = t; i < n; i += blockDim.x) {
    uint32_t kk = useLds ? sh[i] : keys[i];
    if (kk >= p) out_s[idxs[i]] = key2f(kk);
  }
}

extern "C" void kernel_launch(void* const* d_in, const int* in_sizes, int n_in,
                              void* d_out, int out_size, void* d_ws, size_t ws_size,
                              hipStream_t stream) {
  const float* in = (const float*)d_in[0];
  const int* kptr = (const int*)d_in[1];
  float* out = (float*)d_out;
  int n = in_sizes[0];
  int n4 = n >> 2;
  int ntail = n & 3;

  uint32_t* ws = (uint32_t*)d_ws;
  uint32_t* ctrl = ws + CTRL_OFF;
  size_t ws_words = ws_size / 4;
  uint32_t cap = 0;
  if (ws_words > CAND_OFF + 2) cap = (uint32_t)((ws_words - CAND_OFF) / 2);
  uint32_t* keys = ws + CAND_OFF;
  uint32_t* idxs = keys + cap;

  const int HB = 1024;  // hist/fb grid

  hipMemsetAsync(d_ws, 0, ZERO_WORDS * sizeof(uint32_t), stream);
  k_sample<<<SAMPLE_BLOCKS, 256, 0, stream>>>((const float4*)in, n4, kptr,
                                              (uint32_t)n, ws);
  k_hist_tail<<<HB, 256, 0, stream>>>((const float4*)in, n4, ntail, in, kptr,
                                      ws, HB, (uint32_t)n);
  k_fb<<<HB, 256, 0, stream>>>((const float4*)in, n4, ntail, in, kptr,
                               ws, HB, (uint32_t)n);
  k_apply_gather<<<4096, 256, 0, stream>>>((const float4*)in, (float4*)out,
                                           n4, ntail, in, out, ctrl, keys, idxs, cap);
  k_final<<<1, 1024, 0, stream>>>(ctrl, keys, idxs, cap, out);
}